// Round 7
// baseline (867.013 us; speedup 1.0000x reference)
//
#include <hip/hip_runtime.h>

#define N_NODES  100000
#define N_EDGES  1600000
#define N_GRAPHS 512
#define D_H      128
#define N_LAYERS 3

typedef __attribute__((ext_vector_type(8))) short bf16x8;
typedef __attribute__((ext_vector_type(4))) float f32x4;

__device__ __forceinline__ unsigned short f2bf(float f) {
    unsigned int u = __float_as_uint(f);
    u += 0x7fffu + ((u >> 16) & 1u);          // RNE
    return (unsigned short)(u >> 16);
}
__device__ __forceinline__ float bf2f(unsigned short h) {
    return __uint_as_float(((unsigned int)h) << 16);
}
__device__ __forceinline__ float bflo(unsigned v) { return __uint_as_float(v << 16); }
__device__ __forceinline__ float bfhi(unsigned v) { return __uint_as_float(v & 0xffff0000u); }

#define BM  128
#define BKP 72   // 64 + 8 pad ushorts (144B stride -> 2-way max, free)
#define AGP 132  // 128 + 4 pad ushorts (264B stride -> conflict-free b128)

// ---------------------------------------------------------------------------
// Input projection GEMM (fp32 A converted in staging, Ktot=128)
// ---------------------------------------------------------------------------
__global__ __launch_bounds__(256) void gemm_in(
    const float* __restrict__ Af, const unsigned short* __restrict__ BT,
    const float* __restrict__ bias, unsigned short* out, int M)
{
    __shared__ unsigned short As[BM][BKP];
    __shared__ unsigned short Bs[128][BKP];

    const int t    = threadIdx.x;
    const int wave = t >> 6, lane = t & 63;
    const int wr   = wave >> 1, wc = wave & 1;
    const int row0 = blockIdx.x * BM;

    f32x4 acc[4][4];
#pragma unroll
    for (int m = 0; m < 4; m++)
#pragma unroll
        for (int n = 0; n < 4; n++) acc[m][n] = (f32x4)0.f;

    for (int s = 0; s < 2; s++) {
        const int kb = s * 64;
        __syncthreads();
#pragma unroll
        for (int it = 0; it < 4; it++) {
            const int idx = t + it * 256;
            const int r = idx >> 3, c8 = (idx & 7) * 8;
            uint4 o = make_uint4(0, 0, 0, 0);
            if (row0 + r < M) {
                const float* p = &Af[(size_t)(row0 + r) * D_H + kb + c8];
                const float4 v0 = *(const float4*)p;
                const float4 v1 = *(const float4*)(p + 4);
                o.x = (unsigned)f2bf(v0.x) | ((unsigned)f2bf(v0.y) << 16);
                o.y = (unsigned)f2bf(v0.z) | ((unsigned)f2bf(v0.w) << 16);
                o.z = (unsigned)f2bf(v1.x) | ((unsigned)f2bf(v1.y) << 16);
                o.w = (unsigned)f2bf(v1.z) | ((unsigned)f2bf(v1.w) << 16);
            }
            *(uint4*)&As[r][c8] = o;
        }
#pragma unroll
        for (int it = 0; it < 4; it++) {
            const int idx = t + it * 256;
            const int n = idx >> 3, c8 = (idx & 7) * 8;
            *(uint4*)&Bs[n][c8] = *(const uint4*)&BT[(size_t)n * 128 + kb + c8];
        }
        __syncthreads();

#pragma unroll
        for (int kk = 0; kk < 64; kk += 32) {
            const int koff = kk + (lane >> 4) * 8;
            bf16x8 af[4], bfr[4];
#pragma unroll
            for (int m = 0; m < 4; m++)
                af[m] = *(const bf16x8*)&As[wr * 64 + m * 16 + (lane & 15)][koff];
#pragma unroll
            for (int n = 0; n < 4; n++)
                bfr[n] = *(const bf16x8*)&Bs[wc * 64 + n * 16 + (lane & 15)][koff];
#pragma unroll
            for (int m = 0; m < 4; m++)
#pragma unroll
                for (int n = 0; n < 4; n++)
                    acc[m][n] = __builtin_amdgcn_mfma_f32_16x16x32_bf16(
                        af[m], bfr[n], acc[m][n], 0, 0, 0);
        }
    }

    float bv[4];
#pragma unroll
    for (int n = 0; n < 4; n++) bv[n] = bias[wc * 64 + n * 16 + (lane & 15)];
#pragma unroll
    for (int m = 0; m < 4; m++) {
#pragma unroll
        for (int j = 0; j < 4; j++) {
            const int row = row0 + wr * 64 + m * 16 + (lane >> 4) * 4 + j;
            if (row < M) {
#pragma unroll
                for (int n = 0; n < 4; n++) {
                    const int col = wc * 64 + n * 16 + (lane & 15);
                    out[(size_t)row * D_H + col] = f2bf(fmaxf(acc[m][n][j] + bv[n], 0.f));
                }
            }
        }
    }
}

// ---------------------------------------------------------------------------
// Fused SAGE layer: gather-mean into LDS Agg tile, then
// out = relu( Agg@BT[:,0:128] + h@BT[:,128:256] + bias ).
// Phase A (gather, memory pipe) of one block overlaps Phase B (MFMA) of the
// other block on the same CU (2 blocks/CU at 69KB LDS).
// ---------------------------------------------------------------------------
__global__ __launch_bounds__(256) void layer_fused(
    const unsigned short* __restrict__ h, const int* __restrict__ csr,
    const int* __restrict__ rp, const int* __restrict__ deg,
    const float* __restrict__ inv, const unsigned short* __restrict__ BT,
    const float* __restrict__ bias, unsigned short* __restrict__ out, int M)
{
    __shared__ unsigned short Agg[BM][AGP];
    __shared__ unsigned short As[BM][BKP];
    __shared__ unsigned short Bs[128][BKP];

    const int t    = threadIdx.x;
    const int wave = t >> 6, lane = t & 63;
    const int wr   = wave >> 1, wc = wave & 1;
    const int grp  = lane >> 4;            // 0..3
    const int fl   = (lane & 15) * 8;      // 8 bf16 = 16B per lane
    const int row0 = blockIdx.x * BM;

    f32x4 acc[4][4];
#pragma unroll
    for (int m = 0; m < 4; m++)
#pragma unroll
        for (int n = 0; n < 4; n++) acc[m][n] = (f32x4)0.f;

    // ---- Phase A: gather-mean 32 rows per wave into Agg ----
    for (int i = 0; i < 32; i++) {
        const int r = wave * 32 + i;
        const int n = row0 + r;
        if (n < M) {
            const int s0 = rp[n];
            const int s1 = s0 + deg[n];
            float a[8];
#pragma unroll
            for (int k = 0; k < 8; k++) a[k] = 0.f;
            for (int j = s0 + grp; j < s1; j += 4) {
                const int s = csr[j];
                const uint4 v = *(const uint4*)&h[(size_t)s * D_H + fl];
                a[0] += bflo(v.x); a[1] += bfhi(v.x);
                a[2] += bflo(v.y); a[3] += bfhi(v.y);
                a[4] += bflo(v.z); a[5] += bfhi(v.z);
                a[6] += bflo(v.w); a[7] += bfhi(v.w);
            }
#pragma unroll
            for (int k = 0; k < 8; k++) a[k] += __shfl_xor(a[k], 16, 64);
#pragma unroll
            for (int k = 0; k < 8; k++) a[k] += __shfl_xor(a[k], 32, 64);
            if (grp == 0) {
                const float sc = inv[n];
                uint4 o;
                o.x = (unsigned)f2bf(a[0] * sc) | ((unsigned)f2bf(a[1] * sc) << 16);
                o.y = (unsigned)f2bf(a[2] * sc) | ((unsigned)f2bf(a[3] * sc) << 16);
                o.z = (unsigned)f2bf(a[4] * sc) | ((unsigned)f2bf(a[5] * sc) << 16);
                o.w = (unsigned)f2bf(a[6] * sc) | ((unsigned)f2bf(a[7] * sc) << 16);
                *(uint4*)&Agg[r][fl] = o;
            }
        } else if (grp == 0) {
            *(uint4*)&Agg[r][fl] = make_uint4(0, 0, 0, 0);
        }
    }

    // ---- Phase B: GEMM over concat-K [Agg | h] ----
    for (int s = 0; s < 4; s++) {
        const int kb = s * 64;
        __syncthreads();
        if (s >= 2) {
            const int ka = kb & 127;
#pragma unroll
            for (int it = 0; it < 4; it++) {
                const int idx = t + it * 256;
                const int r = idx >> 3, c8 = (idx & 7) * 8;
                uint4 v = make_uint4(0, 0, 0, 0);
                if (row0 + r < M)
                    v = *(const uint4*)&h[(size_t)(row0 + r) * D_H + ka + c8];
                *(uint4*)&As[r][c8] = v;
            }
        }
#pragma unroll
        for (int it = 0; it < 4; it++) {
            const int idx = t + it * 256;
            const int n = idx >> 3, c8 = (idx & 7) * 8;
            *(uint4*)&Bs[n][c8] = *(const uint4*)&BT[(size_t)n * 256 + kb + c8];
        }
        __syncthreads();

#pragma unroll
        for (int kk = 0; kk < 64; kk += 32) {
            const int koff = kk + (lane >> 4) * 8;
            bf16x8 af[4], bfr[4];
            if (s < 2) {
#pragma unroll
                for (int m = 0; m < 4; m++)
                    af[m] = *(const bf16x8*)&Agg[wr * 64 + m * 16 + (lane & 15)][kb + koff];
            } else {
#pragma unroll
                for (int m = 0; m < 4; m++)
                    af[m] = *(const bf16x8*)&As[wr * 64 + m * 16 + (lane & 15)][koff];
            }
#pragma unroll
            for (int n = 0; n < 4; n++)
                bfr[n] = *(const bf16x8*)&Bs[wc * 64 + n * 16 + (lane & 15)][koff];
#pragma unroll
            for (int m = 0; m < 4; m++)
#pragma unroll
                for (int n = 0; n < 4; n++)
                    acc[m][n] = __builtin_amdgcn_mfma_f32_16x16x32_bf16(
                        af[m], bfr[n], acc[m][n], 0, 0, 0);
        }
    }

    float bv[4];
#pragma unroll
    for (int n = 0; n < 4; n++) bv[n] = bias[wc * 64 + n * 16 + (lane & 15)];
#pragma unroll
    for (int m = 0; m < 4; m++) {
#pragma unroll
        for (int j = 0; j < 4; j++) {
            const int row = row0 + wr * 64 + m * 16 + (lane >> 4) * 4 + j;
            if (row < M) {
#pragma unroll
                for (int n = 0; n < 4; n++) {
                    const int col = wc * 64 + n * 16 + (lane & 15);
                    out[(size_t)row * D_H + col] = f2bf(fmaxf(acc[m][n][j] + bv[n], 0.f));
                }
            }
        }
    }
}

// ---------------------------------------------------------------------------
// Weight prep: transposed bf16 weights
// ---------------------------------------------------------------------------
__global__ __launch_bounds__(256) void prep_bt(
    const float* __restrict__ W_in, const float* __restrict__ Wl,
    const float* __restrict__ Wr, unsigned short* __restrict__ BTin,
    unsigned short* __restrict__ BTl)
{
    const int i = blockIdx.x * blockDim.x + threadIdx.x;
    if (i < 128 * 128) {
        const int n = i >> 7, k = i & 127;
        BTin[n * 128 + k] = f2bf(W_in[k * 128 + n]);
    } else if (i < 128 * 128 + N_LAYERS * 128 * 256) {
        const int j = i - 128 * 128;
        const int l = j >> 15, r = j & 32767;
        const int n = r >> 8, k = r & 255;
        const float v = (k < 128) ? Wl[(size_t)l * 16384 + k * 128 + n]
                                  : Wr[(size_t)l * 16384 + (k - 128) * 128 + n];
        BTl[(size_t)l * 32768 + n * 256 + k] = f2bf(v);
    }
}

// ---------------------------------------------------------------------------
// CSR build via 256-bucket binning (bucket = dst>>9, 512 nodes each).
// ---------------------------------------------------------------------------
#define NBUK 256
#define EPB  8192
#define NBLK ((N_EDGES + EPB - 1) / EPB)     // 196

__global__ __launch_bounds__(256) void csr_count(
    const int* __restrict__ dst, int* __restrict__ cntMat)
{
    __shared__ int cnt[NBUK];
    cnt[threadIdx.x] = 0;
    __syncthreads();
    const int e0 = blockIdx.x * EPB;
    const int e1 = min(e0 + EPB, N_EDGES);
    for (int e = e0 + threadIdx.x; e < e1; e += 256)
        atomicAdd(&cnt[dst[e] >> 9], 1);
    __syncthreads();
    cntMat[threadIdx.x * NBLK + blockIdx.x] = cnt[threadIdx.x];
}

__global__ __launch_bounds__(256) void csr_scan_bucket(
    const int* __restrict__ cntMat, int* __restrict__ basMat, int* __restrict__ btot)
{
    __shared__ int s[256];
    const int b = blockIdx.x, t = threadIdx.x;
    const int v = (t < NBLK) ? cntMat[b * NBLK + t] : 0;
    s[t] = v; __syncthreads();
    for (int st = 1; st < 256; st <<= 1) {
        const int u = (t >= st) ? s[t - st] : 0;
        __syncthreads();
        s[t] += u;
        __syncthreads();
    }
    if (t < NBLK) basMat[b * NBLK + t] = s[t] - v;
    if (t == 255) btot[b] = s[255];
}

__global__ __launch_bounds__(256) void csr_scan_top(
    const int* __restrict__ btot, int* __restrict__ bbase)
{
    __shared__ int s[NBUK];
    const int t = threadIdx.x;
    const int v = btot[t];
    s[t] = v; __syncthreads();
    for (int st = 1; st < 256; st <<= 1) {
        const int u = (t >= st) ? s[t - st] : 0;
        __syncthreads();
        s[t] += u;
        __syncthreads();
    }
    bbase[t] = s[t] - v;
}

__global__ __launch_bounds__(256) void csr_scatter(
    const int* __restrict__ src, const int* __restrict__ dst,
    const int* __restrict__ basMat, const int* __restrict__ bbase,
    int2* __restrict__ binned)
{
    __shared__ int cur[NBUK];
    cur[threadIdx.x] = bbase[threadIdx.x] + basMat[threadIdx.x * NBLK + blockIdx.x];
    __syncthreads();
    const int e0 = blockIdx.x * EPB;
    const int e1 = min(e0 + EPB, N_EDGES);
    for (int e = e0 + threadIdx.x; e < e1; e += 256) {
        const int d = dst[e];
        const int pos = atomicAdd(&cur[d >> 9], 1);
        binned[pos] = make_int2(src[e], d);
    }
}

__global__ __launch_bounds__(256) void csr_build(
    const int2* __restrict__ binned, const int* __restrict__ bbase,
    const int* __restrict__ btot, int* __restrict__ rp, int* __restrict__ deg,
    float* __restrict__ inv, int* __restrict__ csr)
{
    __shared__ int hist[512];
    __shared__ int psc[256];
    __shared__ int cur[512];
    const int b = blockIdx.x, t = threadIdx.x;
    const int base = bbase[b];
    const int cntE = btot[b];
    const int n0 = b << 9;

    hist[t] = 0; hist[t + 256] = 0;
    __syncthreads();
    for (int i = t; i < cntE; i += 256)
        atomicAdd(&hist[binned[base + i].y - n0], 1);
    __syncthreads();

    const int h0 = hist[2 * t], h1 = hist[2 * t + 1];
    const int own = h0 + h1;
    psc[t] = own; __syncthreads();
    for (int st = 1; st < 256; st <<= 1) {
        const int u = (t >= st) ? psc[t - st] : 0;
        __syncthreads();
        psc[t] += u;
        __syncthreads();
    }
    const int pairExcl = psc[t] - own;
    cur[2 * t]     = pairExcl;
    cur[2 * t + 1] = pairExcl + h0;
    const int node0 = n0 + 2 * t, node1 = n0 + 2 * t + 1;
    if (node0 < N_NODES) {
        rp[node0] = base + pairExcl; deg[node0] = h0;
        inv[node0] = 1.f / fmaxf((float)h0, 1.f);
    }
    if (node1 < N_NODES) {
        rp[node1] = base + pairExcl + h0; deg[node1] = h1;
        inv[node1] = 1.f / fmaxf((float)h1, 1.f);
    }
    __syncthreads();
    for (int i = t; i < cntE; i += 256) {
        const int2 r = binned[base + i];
        const int pos = atomicAdd(&cur[r.y - n0], 1);
        csr[base + pos] = r.x;
    }
}

// ---------------------------------------------------------------------------
// Pooling: one block per graph (batch sorted), direct mean+max
// ---------------------------------------------------------------------------
__global__ __launch_bounds__(256) void pool_graph(
    const unsigned short* __restrict__ h, const int* __restrict__ batch,
    float* __restrict__ meanb, float* __restrict__ maxb)
{
    __shared__ int bounds[2];
    __shared__ float2 ssum[256];
    __shared__ float2 smax[256];
    const int g = blockIdx.x, t = threadIdx.x;
    if (t < 2) {
        const int v = g + t;
        int lo = 0, hi = N_NODES;
        while (lo < hi) { const int m = (lo + hi) >> 1; if (batch[m] < v) lo = m + 1; else hi = m; }
        bounds[t] = lo;
    }
    __syncthreads();
    const int n0 = bounds[0], n1 = bounds[1];
    const int f2 = t & 63;
    const int sub = t >> 6;

    float sx = 0.f, sy = 0.f, mx = 0.f, my = 0.f;   // h >= 0 post-relu
    for (int n = n0 + sub; n < n1; n += 4) {
        const unsigned v = *(const unsigned*)&h[(size_t)n * D_H + f2 * 2];
        const float x = bflo(v), y = bfhi(v);
        sx += x; sy += y;
        mx = fmaxf(mx, x); my = fmaxf(my, y);
    }
    ssum[t] = make_float2(sx, sy);
    smax[t] = make_float2(mx, my);
    __syncthreads();
    if (sub == 0) {
        const float2 s0 = ssum[t], s1 = ssum[t + 64], s2 = ssum[t + 128], s3 = ssum[t + 192];
        const float2 m0 = smax[t], m1 = smax[t + 64], m2 = smax[t + 128], m3 = smax[t + 192];
        const float ic = 1.f / fmaxf((float)(n1 - n0), 1.f);
        meanb[g * D_H + f2 * 2]     = (s0.x + s1.x + s2.x + s3.x) * ic;
        meanb[g * D_H + f2 * 2 + 1] = (s0.y + s1.y + s2.y + s3.y) * ic;
        maxb[g * D_H + f2 * 2]      = fmaxf(fmaxf(m0.x, m1.x), fmaxf(m2.x, m3.x));
        maxb[g * D_H + f2 * 2 + 1]  = fmaxf(fmaxf(m0.y, m1.y), fmaxf(m2.y, m3.y));
    }
}

// ---------------------------------------------------------------------------
// Head MLP (fp32): z = [mean, max, gf]
// ---------------------------------------------------------------------------
__global__ __launch_bounds__(128) void mlp_kernel(
    const float* __restrict__ meanb, const float* __restrict__ maxb,
    const float* __restrict__ gf,
    const float* __restrict__ W1, const float* __restrict__ b1,
    const float* __restrict__ W2, const float* __restrict__ b2,
    float* __restrict__ out)
{
    __shared__ float z[2 * D_H + 32];
    __shared__ float z1[D_H];
    const int g = blockIdx.x, t = threadIdx.x;
    z[t]       = meanb[g * D_H + t];
    z[D_H + t] = maxb[g * D_H + t];
    if (t < 32) z[2 * D_H + t] = gf[g * 32 + t];
    __syncthreads();
    float a = b1[t];
    for (int k = 0; k < 2 * D_H + 32; k++) a += z[k] * W1[k * D_H + t];
    a = fmaxf(a, 0.f);
    z1[t] = a;
    __syncthreads();
    float o = b2[t];
    for (int k = 0; k < D_H; k++) o += z1[k] * W2[k * D_H + t];
    out[g * D_H + t] = fmaxf(o, 0.f);
}

// ---------------------------------------------------------------------------
extern "C" void kernel_launch(void* const* d_in, const int* in_sizes, int n_in,
                              void* d_out, int out_size, void* d_ws, size_t ws_size,
                              hipStream_t stream)
{
    const float* x     = (const float*)d_in[0];
    const int*   ei    = (const int*)d_in[1];
    const int*   batch = (const int*)d_in[2];
    const float* gf    = (const float*)d_in[3];
    const float* W_in  = (const float*)d_in[4];
    const float* b_in  = (const float*)d_in[5];
    const float* Wl    = (const float*)d_in[6];
    const float* bl    = (const float*)d_in[7];
    const float* Wr    = (const float*)d_in[8];
    const float* W1    = (const float*)d_in[9];
    const float* b1    = (const float*)d_in[10];
    const float* W2    = (const float*)d_in[11];
    const float* b2    = (const float*)d_in[12];
    float* out = (float*)d_out;

    const int* srcI = ei;
    const int* dstI = ei + N_EDGES;

    char* ws = (char*)d_ws;
    size_t off = 0;
    auto alloc = [&](size_t bytes) {
        char* p = ws + off;
        off += (bytes + 511) / 512 * 512;
        return p;
    };
    const size_t hB16 = (size_t)N_NODES * D_H * sizeof(unsigned short);
    unsigned short* bufA = (unsigned short*)alloc(hB16);
    unsigned short* bufB = (unsigned short*)alloc(hB16);
    unsigned short* BTin = (unsigned short*)alloc(128 * 128 * sizeof(unsigned short));
    unsigned short* BTl  = (unsigned short*)alloc((size_t)N_LAYERS * 128 * 256 * sizeof(unsigned short));
    int*   degI   = (int*)alloc(N_NODES * sizeof(int));
    float* inv    = (float*)alloc(N_NODES * sizeof(float));
    int*   rp     = (int*)alloc(N_NODES * sizeof(int));
    int*   csr    = (int*)alloc((size_t)N_EDGES * sizeof(int));
    int2*  binned = (int2*)alloc((size_t)N_EDGES * sizeof(int2));
    int*   cntMat = (int*)alloc((size_t)NBUK * NBLK * sizeof(int));
    int*   basMat = (int*)alloc((size_t)NBUK * NBLK * sizeof(int));
    int*   btot   = (int*)alloc(NBUK * sizeof(int));
    int*   bbase  = (int*)alloc(NBUK * sizeof(int));
    float* meanb  = (float*)alloc(N_GRAPHS * D_H * sizeof(float));
    float* maxb   = (float*)alloc(N_GRAPHS * D_H * sizeof(float));

    // CSR build (atomic-free, binned)
    csr_count<<<NBLK, 256, 0, stream>>>(dstI, cntMat);
    csr_scan_bucket<<<NBUK, 256, 0, stream>>>(cntMat, basMat, btot);
    csr_scan_top<<<1, 256, 0, stream>>>(btot, bbase);
    csr_scatter<<<NBLK, 256, 0, stream>>>(srcI, dstI, basMat, bbase, binned);
    csr_build<<<NBUK, 256, 0, stream>>>(binned, bbase, btot, rp, degI, inv, csr);

    prep_bt<<<(128 * 128 + N_LAYERS * 128 * 256 + 255) / 256, 256, 0, stream>>>(
        W_in, Wl, Wr, BTin, BTl);

    const int gblocks = (N_NODES + BM - 1) / BM;
    gemm_in<<<gblocks, 256, 0, stream>>>(x, BTin, b_in, bufA, N_NODES);

    unsigned short* h  = bufA;
    unsigned short* hn = bufB;
    for (int l = 0; l < N_LAYERS; l++) {
        layer_fused<<<gblocks, 256, 0, stream>>>(h, csr, rp, degI, inv,
                                                 BTl + (size_t)l * 32768,
                                                 bl + (size_t)l * D_H, hn, N_NODES);
        unsigned short* tmp = h; h = hn; hn = tmp;
    }

    pool_graph<<<N_GRAPHS, 256, 0, stream>>>(h, batch, meanb, maxb);
    mlp_kernel<<<N_GRAPHS, 128, 0, stream>>>(meanb, maxb, gf, W1, b1, W2, b2, out);
}

// Round 8
// 444.070 us; speedup vs baseline: 1.9524x; 1.9524x over previous
//
#include <hip/hip_runtime.h>

#define N_NODES  100000
#define N_EDGES  1600000
#define N_GRAPHS 512
#define D_H      128
#define N_LAYERS 3

typedef __attribute__((ext_vector_type(8))) short bf16x8;
typedef __attribute__((ext_vector_type(4))) float f32x4;

__device__ __forceinline__ unsigned short f2bf(float f) {
    unsigned int u = __float_as_uint(f);
    u += 0x7fffu + ((u >> 16) & 1u);          // RNE
    return (unsigned short)(u >> 16);
}
__device__ __forceinline__ float bf2f(unsigned short h) {
    return __uint_as_float(((unsigned int)h) << 16);
}
__device__ __forceinline__ float bflo(unsigned v) { return __uint_as_float(v << 16); }
__device__ __forceinline__ float bfhi(unsigned v) { return __uint_as_float(v & 0xffff0000u); }

#define BM 128

// ---------------------------------------------------------------------------
// LDS-free streaming MFMA GEMM. 128x128 tile, 4 waves (64x64/wave).
// A/B fragments are loaded DIRECTLY from global memory in MFMA layout
// (16B/lane, 16 rows x 128B contiguous per K-step -> full-line coalescing).
// No __shared__, no barriers; occupancy is VGPR-limited, latency hidden by
// wave TLP. B (BT, n-major k-contig) is L2-resident across blocks.
// MODE 0: A = Af (fp32, Ktot=128), converted in registers.
// MODE 1: A = concat-K [A0 | A1] (bf16, Ktot=256). No output aliasing!
// ---------------------------------------------------------------------------
template <int MODE>
__global__ __launch_bounds__(256) void gemm_direct(
    const float* __restrict__ Af, const unsigned short* __restrict__ A0,
    const unsigned short* __restrict__ A1, const unsigned short* __restrict__ BT,
    const float* __restrict__ bias, unsigned short* __restrict__ out, int M)
{
    constexpr int Ktot = (MODE == 0) ? 128 : 256;
    const int t    = threadIdx.x;
    const int wave = t >> 6, lane = t & 63;
    const int wr   = wave >> 1, wc = wave & 1;
    const int l15  = lane & 15;
    const int kgrp = (lane >> 4) * 8;
    const int row0 = blockIdx.x * BM;

    f32x4 acc[4][4];
#pragma unroll
    for (int m = 0; m < 4; m++)
#pragma unroll
        for (int n = 0; n < 4; n++) acc[m][n] = (f32x4)0.f;

    // clamped A-row per m-fragment (OOB rows read row M-1; results discarded)
    int rowc[4];
#pragma unroll
    for (int m = 0; m < 4; m++)
        rowc[m] = min(row0 + wr * 64 + m * 16 + l15, M - 1);

    const int ncol = wc * 64 + l15;

#pragma unroll 1
    for (int s = 0; s < Ktot / 64; s++) {
        const int kb = s * 64;
#pragma unroll
        for (int kk = 0; kk < 64; kk += 32) {
            const int ko = kb + kk + kgrp;
            bf16x8 af[4], bfr[4];
            if (MODE == 0) {
#pragma unroll
                for (int m = 0; m < 4; m++) {
                    const float* p = &Af[(size_t)rowc[m] * D_H + ko];
                    const float4 v0 = *(const float4*)p;
                    const float4 v1 = *(const float4*)(p + 4);
                    unsigned x0 = (unsigned)f2bf(v0.x) | ((unsigned)f2bf(v0.y) << 16);
                    unsigned x1 = (unsigned)f2bf(v0.z) | ((unsigned)f2bf(v0.w) << 16);
                    unsigned x2 = (unsigned)f2bf(v1.x) | ((unsigned)f2bf(v1.y) << 16);
                    unsigned x3 = (unsigned)f2bf(v1.z) | ((unsigned)f2bf(v1.w) << 16);
                    uint4 packed = make_uint4(x0, x1, x2, x3);
                    af[m] = *(const bf16x8*)&packed;
                }
            } else {
                const unsigned short* __restrict__ Asrc = (kb < 128) ? A0 : A1;
                const int ka = (kb & 127) + kk + kgrp;
#pragma unroll
                for (int m = 0; m < 4; m++)
                    af[m] = *(const bf16x8*)&Asrc[(size_t)rowc[m] * D_H + ka];
            }
#pragma unroll
            for (int n = 0; n < 4; n++)
                bfr[n] = *(const bf16x8*)&BT[(size_t)(ncol + n * 16) * Ktot + ko];
#pragma unroll
            for (int m = 0; m < 4; m++)
#pragma unroll
                for (int n = 0; n < 4; n++)
                    acc[m][n] = __builtin_amdgcn_mfma_f32_16x16x32_bf16(
                        af[m], bfr[n], acc[m][n], 0, 0, 0);
        }
    }

    float bv[4];
#pragma unroll
    for (int n = 0; n < 4; n++) bv[n] = bias[wc * 64 + n * 16 + l15];

#pragma unroll
    for (int m = 0; m < 4; m++) {
#pragma unroll
        for (int j = 0; j < 4; j++) {
            const int row = row0 + wr * 64 + m * 16 + (lane >> 4) * 4 + j;
            if (row < M) {
#pragma unroll
                for (int n = 0; n < 4; n++) {
                    const int col = wc * 64 + n * 16 + l15;
                    out[(size_t)row * D_H + col] = f2bf(fmaxf(acc[m][n][j] + bv[n], 0.f));
                }
            }
        }
    }
}

// ---------------------------------------------------------------------------
// Weight prep: transposed bf16 weights
// ---------------------------------------------------------------------------
__global__ __launch_bounds__(256) void prep_bt(
    const float* __restrict__ W_in, const float* __restrict__ Wl,
    const float* __restrict__ Wr, unsigned short* __restrict__ BTin,
    unsigned short* __restrict__ BTl)
{
    const int i = blockIdx.x * blockDim.x + threadIdx.x;
    if (i < 128 * 128) {
        const int n = i >> 7, k = i & 127;
        BTin[n * 128 + k] = f2bf(W_in[k * 128 + n]);
    } else if (i < 128 * 128 + N_LAYERS * 128 * 256) {
        const int j = i - 128 * 128;
        const int l = j >> 15, r = j & 32767;
        const int n = r >> 8, k = r & 255;
        const float v = (k < 128) ? Wl[(size_t)l * 16384 + k * 128 + n]
                                  : Wr[(size_t)l * 16384 + (k - 128) * 128 + n];
        BTl[(size_t)l * 32768 + n * 256 + k] = f2bf(v);
    }
}

// ---------------------------------------------------------------------------
// CSR build via 256-bucket binning (bucket = dst>>9, 512 nodes each).
// ---------------------------------------------------------------------------
#define NBUK 256
#define EPB  8192
#define NBLK ((N_EDGES + EPB - 1) / EPB)     // 196

__global__ __launch_bounds__(256) void csr_count(
    const int* __restrict__ dst, int* __restrict__ cntMat)
{
    __shared__ int cnt[NBUK];
    cnt[threadIdx.x] = 0;
    __syncthreads();
    const int e0 = blockIdx.x * EPB;
    const int e1 = min(e0 + EPB, N_EDGES);
    for (int e = e0 + threadIdx.x; e < e1; e += 256)
        atomicAdd(&cnt[dst[e] >> 9], 1);
    __syncthreads();
    cntMat[threadIdx.x * NBLK + blockIdx.x] = cnt[threadIdx.x];
}

__global__ __launch_bounds__(256) void csr_scan_bucket(
    const int* __restrict__ cntMat, int* __restrict__ basMat, int* __restrict__ btot)
{
    __shared__ int s[256];
    const int b = blockIdx.x, t = threadIdx.x;
    const int v = (t < NBLK) ? cntMat[b * NBLK + t] : 0;
    s[t] = v; __syncthreads();
    for (int st = 1; st < 256; st <<= 1) {
        const int u = (t >= st) ? s[t - st] : 0;
        __syncthreads();
        s[t] += u;
        __syncthreads();
    }
    if (t < NBLK) basMat[b * NBLK + t] = s[t] - v;
    if (t == 255) btot[b] = s[255];
}

__global__ __launch_bounds__(256) void csr_scan_top(
    const int* __restrict__ btot, int* __restrict__ bbase)
{
    __shared__ int s[NBUK];
    const int t = threadIdx.x;
    const int v = btot[t];
    s[t] = v; __syncthreads();
    for (int st = 1; st < 256; st <<= 1) {
        const int u = (t >= st) ? s[t - st] : 0;
        __syncthreads();
        s[t] += u;
        __syncthreads();
    }
    bbase[t] = s[t] - v;
}

__global__ __launch_bounds__(256) void csr_scatter(
    const int* __restrict__ src, const int* __restrict__ dst,
    const int* __restrict__ basMat, const int* __restrict__ bbase,
    int2* __restrict__ binned)
{
    __shared__ int cur[NBUK];
    cur[threadIdx.x] = bbase[threadIdx.x] + basMat[threadIdx.x * NBLK + blockIdx.x];
    __syncthreads();
    const int e0 = blockIdx.x * EPB;
    const int e1 = min(e0 + EPB, N_EDGES);
    for (int e = e0 + threadIdx.x; e < e1; e += 256) {
        const int d = dst[e];
        const int pos = atomicAdd(&cur[d >> 9], 1);
        binned[pos] = make_int2(src[e], d);
    }
}

__global__ __launch_bounds__(256) void csr_build(
    const int2* __restrict__ binned, const int* __restrict__ bbase,
    const int* __restrict__ btot, int* __restrict__ rp, int* __restrict__ deg,
    float* __restrict__ inv, int* __restrict__ csr)
{
    __shared__ int hist[512];
    __shared__ int psc[256];
    __shared__ int cur[512];
    const int b = blockIdx.x, t = threadIdx.x;
    const int base = bbase[b];
    const int cntE = btot[b];
    const int n0 = b << 9;

    hist[t] = 0; hist[t + 256] = 0;
    __syncthreads();
    for (int i = t; i < cntE; i += 256)
        atomicAdd(&hist[binned[base + i].y - n0], 1);
    __syncthreads();

    const int h0 = hist[2 * t], h1 = hist[2 * t + 1];
    const int own = h0 + h1;
    psc[t] = own; __syncthreads();
    for (int st = 1; st < 256; st <<= 1) {
        const int u = (t >= st) ? psc[t - st] : 0;
        __syncthreads();
        psc[t] += u;
        __syncthreads();
    }
    const int pairExcl = psc[t] - own;
    cur[2 * t]     = pairExcl;
    cur[2 * t + 1] = pairExcl + h0;
    const int node0 = n0 + 2 * t, node1 = n0 + 2 * t + 1;
    if (node0 < N_NODES) {
        rp[node0] = base + pairExcl; deg[node0] = h0;
        inv[node0] = 1.f / fmaxf((float)h0, 1.f);
    }
    if (node1 < N_NODES) {
        rp[node1] = base + pairExcl + h0; deg[node1] = h1;
        inv[node1] = 1.f / fmaxf((float)h1, 1.f);
    }
    __syncthreads();
    for (int i = t; i < cntE; i += 256) {
        const int2 r = binned[base + i];
        const int pos = atomicAdd(&cur[r.y - n0], 1);
        csr[base + pos] = r.x;
    }
}

// ---------------------------------------------------------------------------
// Gather-mean: wave per node, 4x16-lane groups, uint4 per lane (R6 version)
// ---------------------------------------------------------------------------
__global__ __launch_bounds__(256) void gather_mean(
    const unsigned short* __restrict__ h, const int* __restrict__ csr,
    const int* __restrict__ rp, const int* __restrict__ deg,
    const float* __restrict__ inv, unsigned short* __restrict__ agg)
{
    const int wave   = (blockIdx.x * blockDim.x + threadIdx.x) >> 6;
    const int lane   = threadIdx.x & 63;
    const int grp    = lane >> 4;            // 0..3
    const int fl     = (lane & 15) * 8;      // feature base (8 bf16 = 16B)
    const int nwaves = (gridDim.x * blockDim.x) >> 6;

    for (int n = wave; n < N_NODES; n += nwaves) {
        const int s0 = rp[n];
        const int s1 = s0 + deg[n];
        float a[8];
#pragma unroll
        for (int k = 0; k < 8; k++) a[k] = 0.f;

        for (int j = s0 + grp; j < s1; j += 4) {
            const int s = csr[j];
            const uint4 v = *(const uint4*)&h[(size_t)s * D_H + fl];
            a[0] += bflo(v.x); a[1] += bfhi(v.x);
            a[2] += bflo(v.y); a[3] += bfhi(v.y);
            a[4] += bflo(v.z); a[5] += bfhi(v.z);
            a[6] += bflo(v.w); a[7] += bfhi(v.w);
        }
#pragma unroll
        for (int k = 0; k < 8; k++) a[k] += __shfl_xor(a[k], 16, 64);
#pragma unroll
        for (int k = 0; k < 8; k++) a[k] += __shfl_xor(a[k], 32, 64);

        if (grp == 0) {
            const float sc = inv[n];
            uint4 o;
            o.x = (unsigned)f2bf(a[0] * sc) | ((unsigned)f2bf(a[1] * sc) << 16);
            o.y = (unsigned)f2bf(a[2] * sc) | ((unsigned)f2bf(a[3] * sc) << 16);
            o.z = (unsigned)f2bf(a[4] * sc) | ((unsigned)f2bf(a[5] * sc) << 16);
            o.w = (unsigned)f2bf(a[6] * sc) | ((unsigned)f2bf(a[7] * sc) << 16);
            *(uint4*)&agg[(size_t)n * D_H + fl] = o;
        }
    }
}

// ---------------------------------------------------------------------------
// Pooling: one block per graph (batch sorted), direct mean+max
// ---------------------------------------------------------------------------
__global__ __launch_bounds__(256) void pool_graph(
    const unsigned short* __restrict__ h, const int* __restrict__ batch,
    float* __restrict__ meanb, float* __restrict__ maxb)
{
    __shared__ int bounds[2];
    __shared__ float2 ssum[256];
    __shared__ float2 smax[256];
    const int g = blockIdx.x, t = threadIdx.x;
    if (t < 2) {
        const int v = g + t;
        int lo = 0, hi = N_NODES;
        while (lo < hi) { const int m = (lo + hi) >> 1; if (batch[m] < v) lo = m + 1; else hi = m; }
        bounds[t] = lo;
    }
    __syncthreads();
    const int n0 = bounds[0], n1 = bounds[1];
    const int f2 = t & 63;
    const int sub = t >> 6;

    float sx = 0.f, sy = 0.f, mx = 0.f, my = 0.f;   // h >= 0 post-relu
    for (int n = n0 + sub; n < n1; n += 4) {
        const unsigned v = *(const unsigned*)&h[(size_t)n * D_H + f2 * 2];
        const float x = bflo(v), y = bfhi(v);
        sx += x; sy += y;
        mx = fmaxf(mx, x); my = fmaxf(my, y);
    }
    ssum[t] = make_float2(sx, sy);
    smax[t] = make_float2(mx, my);
    __syncthreads();
    if (sub == 0) {
        const float2 s0 = ssum[t], s1 = ssum[t + 64], s2 = ssum[t + 128], s3 = ssum[t + 192];
        const float2 m0 = smax[t], m1 = smax[t + 64], m2 = smax[t + 128], m3 = smax[t + 192];
        const float ic = 1.f / fmaxf((float)(n1 - n0), 1.f);
        meanb[g * D_H + f2 * 2]     = (s0.x + s1.x + s2.x + s3.x) * ic;
        meanb[g * D_H + f2 * 2 + 1] = (s0.y + s1.y + s2.y + s3.y) * ic;
        maxb[g * D_H + f2 * 2]      = fmaxf(fmaxf(m0.x, m1.x), fmaxf(m2.x, m3.x));
        maxb[g * D_H + f2 * 2 + 1]  = fmaxf(fmaxf(m0.y, m1.y), fmaxf(m2.y, m3.y));
    }
}

// ---------------------------------------------------------------------------
// Head MLP (fp32): z = [mean, max, gf]
// ---------------------------------------------------------------------------
__global__ __launch_bounds__(128) void mlp_kernel(
    const float* __restrict__ meanb, const float* __restrict__ maxb,
    const float* __restrict__ gf,
    const float* __restrict__ W1, const float* __restrict__ b1,
    const float* __restrict__ W2, const float* __restrict__ b2,
    float* __restrict__ out)
{
    __shared__ float z[2 * D_H + 32];
    __shared__ float z1[D_H];
    const int g = blockIdx.x, t = threadIdx.x;
    z[t]       = meanb[g * D_H + t];
    z[D_H + t] = maxb[g * D_H + t];
    if (t < 32) z[2 * D_H + t] = gf[g * 32 + t];
    __syncthreads();
    float a = b1[t];
    for (int k = 0; k < 2 * D_H + 32; k++) a += z[k] * W1[k * D_H + t];
    a = fmaxf(a, 0.f);
    z1[t] = a;
    __syncthreads();
    float o = b2[t];
    for (int k = 0; k < D_H; k++) o += z1[k] * W2[k * D_H + t];
    out[g * D_H + t] = fmaxf(o, 0.f);
}

// ---------------------------------------------------------------------------
extern "C" void kernel_launch(void* const* d_in, const int* in_sizes, int n_in,
                              void* d_out, int out_size, void* d_ws, size_t ws_size,
                              hipStream_t stream)
{
    const float* x     = (const float*)d_in[0];
    const int*   ei    = (const int*)d_in[1];
    const int*   batch = (const int*)d_in[2];
    const float* gf    = (const float*)d_in[3];
    const float* W_in  = (const float*)d_in[4];
    const float* b_in  = (const float*)d_in[5];
    const float* Wl    = (const float*)d_in[6];
    const float* bl    = (const float*)d_in[7];
    const float* Wr    = (const float*)d_in[8];
    const float* W1    = (const float*)d_in[9];
    const float* b1    = (const float*)d_in[10];
    const float* W2    = (const float*)d_in[11];
    const float* b2    = (const float*)d_in[12];
    float* out = (float*)d_out;

    const int* srcI = ei;
    const int* dstI = ei + N_EDGES;

    char* ws = (char*)d_ws;
    size_t off = 0;
    auto alloc = [&](size_t bytes) {
        char* p = ws + off;
        off += (bytes + 511) / 512 * 512;
        return p;
    };
    const size_t hB16 = (size_t)N_NODES * D_H * sizeof(unsigned short);
    unsigned short* buf0 = (unsigned short*)alloc(hB16);
    unsigned short* buf1 = (unsigned short*)alloc(hB16);
    unsigned short* buf2 = (unsigned short*)alloc(hB16);
    unsigned short* BTin = (unsigned short*)alloc(128 * 128 * sizeof(unsigned short));
    unsigned short* BTl  = (unsigned short*)alloc((size_t)N_LAYERS * 128 * 256 * sizeof(unsigned short));
    int*   degI   = (int*)alloc(N_NODES * sizeof(int));
    float* inv    = (float*)alloc(N_NODES * sizeof(float));
    int*   rp     = (int*)alloc(N_NODES * sizeof(int));
    int*   csr    = (int*)alloc((size_t)N_EDGES * sizeof(int));
    int2*  binned = (int2*)alloc((size_t)N_EDGES * sizeof(int2));
    int*   cntMat = (int*)alloc((size_t)NBUK * NBLK * sizeof(int));
    int*   basMat = (int*)alloc((size_t)NBUK * NBLK * sizeof(int));
    int*   btot   = (int*)alloc(NBUK * sizeof(int));
    int*   bbase  = (int*)alloc(NBUK * sizeof(int));
    float* meanb  = (float*)alloc(N_GRAPHS * D_H * sizeof(float));
    float* maxb   = (float*)alloc(N_GRAPHS * D_H * sizeof(float));

    // CSR build (atomic-free, binned)
    csr_count<<<NBLK, 256, 0, stream>>>(dstI, cntMat);
    csr_scan_bucket<<<NBUK, 256, 0, stream>>>(cntMat, basMat, btot);
    csr_scan_top<<<1, 256, 0, stream>>>(btot, bbase);
    csr_scatter<<<NBLK, 256, 0, stream>>>(srcI, dstI, basMat, bbase, binned);
    csr_build<<<NBUK, 256, 0, stream>>>(binned, bbase, btot, rp, degI, inv, csr);

    prep_bt<<<(128 * 128 + N_LAYERS * 128 * 256 + 255) / 256, 256, 0, stream>>>(
        W_in, Wl, Wr, BTin, BTl);

    const int gblocks = (N_NODES + BM - 1) / BM;
    // input projection (fp32 x, direct-frag streaming) -> buf0
    gemm_direct<0><<<gblocks, 256, 0, stream>>>(x, nullptr, nullptr, BTin, b_in, buf0, N_NODES);

    // 3-buffer rotation (no aliasing: direct GEMM has no barriers)
    unsigned short* h   = buf0;
    unsigned short* agg = buf1;
    unsigned short* nxt = buf2;
    for (int l = 0; l < N_LAYERS; l++) {
        gather_mean<<<2048, 256, 0, stream>>>(h, csr, rp, degI, inv, agg);
        gemm_direct<1><<<gblocks, 256, 0, stream>>>(nullptr, agg, h, BTl + (size_t)l * 32768,
                                                    bl + (size_t)l * D_H, nxt, N_NODES);
        unsigned short* oldH = h;
        h = nxt;          // new features
        nxt = agg;        // old agg buffer becomes next output
        agg = oldH;       // old h buffer becomes next agg scratch
    }

    pool_graph<<<N_GRAPHS, 256, 0, stream>>>(h, batch, meanb, maxb);
    mlp_kernel<<<N_GRAPHS, 128, 0, stream>>>(meanb, maxb, gf, W1, b1, W2, b2, out);
}

// Round 9
// 395.454 us; speedup vs baseline: 2.1924x; 1.1229x over previous
//
#include <hip/hip_runtime.h>

#define N_NODES  100000
#define N_EDGES  1600000
#define N_GRAPHS 512
#define D_H      128
#define N_LAYERS 3

typedef __attribute__((ext_vector_type(8))) short bf16x8;
typedef __attribute__((ext_vector_type(4))) float f32x4;

__device__ __forceinline__ unsigned short f2bf(float f) {
    unsigned int u = __float_as_uint(f);
    u += 0x7fffu + ((u >> 16) & 1u);          // RNE
    return (unsigned short)(u >> 16);
}
__device__ __forceinline__ float bf2f(unsigned short h) {
    return __uint_as_float(((unsigned int)h) << 16);
}
__device__ __forceinline__ float bflo(unsigned v) { return __uint_as_float(v << 16); }
__device__ __forceinline__ float bfhi(unsigned v) { return __uint_as_float(v & 0xffff0000u); }

#define BM  128
#define BKP 72   // 64 + 8 pad ushorts (144B stride -> 2-way max, free)

// ---------------------------------------------------------------------------
// bf16 MFMA GEMM. A: LDS-staged 128x64 per K-step (R6 layout, conflict-free).
// B: PRE-PACKED in MFMA fragment order -> direct global loads, lane-contiguous
// 1KB per wave instruction, L2-resident (64KB/layer). No LDS for B.
// Packed index: PB[((kblk*8 + nb)*64 + lane)*8 + j],
//   n = nb*16 + (lane&15), k = kblk*32 + (lane>>4)*8 + j.
// MODE 0: A = Af fp32 (Ktot=128), converted during staging.
// MODE 1: A = concat-K [A0 | A1] bf16 (Ktot=256). out may alias A0 (each
// block stages its own A0 rows, barrier-protected, before the epilogue).
// ---------------------------------------------------------------------------
template <int MODE>
__global__ __launch_bounds__(256) void gemm_mfma(
    const float* __restrict__ Af, const unsigned short* A0,
    const unsigned short* A1, const unsigned short* __restrict__ PB,
    const float* __restrict__ bias, unsigned short* out, int M)
{
    constexpr int Ktot = (MODE == 0) ? 128 : 256;
    __shared__ unsigned short As[BM][BKP];

    const int t    = threadIdx.x;
    const int wave = t >> 6, lane = t & 63;
    const int wr   = wave >> 1, wc = wave & 1;
    const int l15  = lane & 15;
    const int row0 = blockIdx.x * BM;

    f32x4 acc[4][4];
#pragma unroll
    for (int m = 0; m < 4; m++)
#pragma unroll
        for (int n = 0; n < 4; n++) acc[m][n] = (f32x4)0.f;

    for (int s = 0; s < (Ktot >> 6); s++) {
        const int kb = s * 64;
        __syncthreads();
        if (MODE == 0) {
#pragma unroll
            for (int it = 0; it < 4; it++) {
                const int idx = t + it * 256;
                const int r = idx >> 3, c8 = (idx & 7) * 8;
                uint4 o = make_uint4(0, 0, 0, 0);
                if (row0 + r < M) {
                    const float* p = &Af[(size_t)(row0 + r) * D_H + kb + c8];
                    const float4 v0 = *(const float4*)p;
                    const float4 v1 = *(const float4*)(p + 4);
                    o.x = (unsigned)f2bf(v0.x) | ((unsigned)f2bf(v0.y) << 16);
                    o.y = (unsigned)f2bf(v0.z) | ((unsigned)f2bf(v0.w) << 16);
                    o.z = (unsigned)f2bf(v1.x) | ((unsigned)f2bf(v1.y) << 16);
                    o.w = (unsigned)f2bf(v1.z) | ((unsigned)f2bf(v1.w) << 16);
                }
                *(uint4*)&As[r][c8] = o;
            }
        } else {
            const unsigned short* Asrc = (kb < 128) ? A0 : A1;
            const int ka = kb & 127;
#pragma unroll
            for (int it = 0; it < 4; it++) {
                const int idx = t + it * 256;
                const int r = idx >> 3, c8 = (idx & 7) * 8;
                uint4 v = make_uint4(0, 0, 0, 0);
                if (row0 + r < M)
                    v = *(const uint4*)&Asrc[(size_t)(row0 + r) * D_H + ka + c8];
                *(uint4*)&As[r][c8] = v;
            }
        }
        __syncthreads();

#pragma unroll
        for (int kk = 0; kk < 64; kk += 32) {
            const int koff = kk + (lane >> 4) * 8;
            const int kblk = (kb + kk) >> 5;
            bf16x8 af[4], bfr[4];
#pragma unroll
            for (int m = 0; m < 4; m++)
                af[m] = *(const bf16x8*)&As[wr * 64 + m * 16 + l15][koff];
#pragma unroll
            for (int n = 0; n < 4; n++)
                bfr[n] = *(const bf16x8*)&PB[(size_t)(((kblk << 3) + (wc << 2) + n) << 9) + lane * 8];
#pragma unroll
            for (int m = 0; m < 4; m++)
#pragma unroll
                for (int n = 0; n < 4; n++)
                    acc[m][n] = __builtin_amdgcn_mfma_f32_16x16x32_bf16(
                        af[m], bfr[n], acc[m][n], 0, 0, 0);
        }
    }

    float bv[4];
#pragma unroll
    for (int n = 0; n < 4; n++) bv[n] = bias[wc * 64 + n * 16 + l15];

#pragma unroll
    for (int m = 0; m < 4; m++) {
#pragma unroll
        for (int j = 0; j < 4; j++) {
            const int row = row0 + wr * 64 + m * 16 + (lane >> 4) * 4 + j;
            if (row < M) {
#pragma unroll
                for (int n = 0; n < 4; n++) {
                    const int col = wc * 64 + n * 16 + l15;
                    out[(size_t)row * D_H + col] = f2bf(fmaxf(acc[m][n][j] + bv[n], 0.f));
                }
            }
        }
    }
}

// ---------------------------------------------------------------------------
// Weight prep: pack transposed bf16 weights in MFMA fragment order.
// PBin: Ktot=128 (kblk 0..3). PBl[l]: Ktot=256 (kblk 0..7; k<128 -> Wl, else Wr).
// ---------------------------------------------------------------------------
__global__ __launch_bounds__(256) void prep_bt(
    const float* __restrict__ W_in, const float* __restrict__ Wl,
    const float* __restrict__ Wr, unsigned short* __restrict__ PBin,
    unsigned short* __restrict__ PBl)
{
    const int i = blockIdx.x * blockDim.x + threadIdx.x;
    if (i < 16384) {
        const int j = i & 7, lane = (i >> 3) & 63, nb = (i >> 9) & 7, kblk = i >> 12;
        const int n = nb * 16 + (lane & 15);
        const int k = kblk * 32 + ((lane >> 4) << 3) + j;
        PBin[i] = f2bf(W_in[k * 128 + n]);
    } else if (i < 16384 + N_LAYERS * 32768) {
        const int i2 = i - 16384;
        const int l = i2 >> 15, r = i2 & 32767;
        const int j = r & 7, lane = (r >> 3) & 63, nb = (r >> 9) & 7, kblk = (r >> 12) & 7;
        const int n = nb * 16 + (lane & 15);
        const int k = kblk * 32 + ((lane >> 4) << 3) + j;
        const float v = (k < 128) ? Wl[(size_t)l * 16384 + k * 128 + n]
                                  : Wr[(size_t)l * 16384 + (k - 128) * 128 + n];
        PBl[(size_t)l * 32768 + r] = f2bf(v);
    }
}

// ---------------------------------------------------------------------------
// CSR build via 256-bucket binning (bucket = dst>>9, 512 nodes each).
// ---------------------------------------------------------------------------
#define NBUK 256
#define EPB  8192
#define NBLK ((N_EDGES + EPB - 1) / EPB)     // 196

__global__ __launch_bounds__(256) void csr_count(
    const int* __restrict__ dst, int* __restrict__ cntMat)
{
    __shared__ int cnt[NBUK];
    cnt[threadIdx.x] = 0;
    __syncthreads();
    const int e0 = blockIdx.x * EPB;
    const int e1 = min(e0 + EPB, N_EDGES);
    for (int e = e0 + threadIdx.x; e < e1; e += 256)
        atomicAdd(&cnt[dst[e] >> 9], 1);
    __syncthreads();
    cntMat[threadIdx.x * NBLK + blockIdx.x] = cnt[threadIdx.x];
}

__global__ __launch_bounds__(256) void csr_scan_bucket(
    const int* __restrict__ cntMat, int* __restrict__ basMat, int* __restrict__ btot)
{
    __shared__ int s[256];
    const int b = blockIdx.x, t = threadIdx.x;
    const int v = (t < NBLK) ? cntMat[b * NBLK + t] : 0;
    s[t] = v; __syncthreads();
    for (int st = 1; st < 256; st <<= 1) {
        const int u = (t >= st) ? s[t - st] : 0;
        __syncthreads();
        s[t] += u;
        __syncthreads();
    }
    if (t < NBLK) basMat[b * NBLK + t] = s[t] - v;
    if (t == 255) btot[b] = s[255];
}

__global__ __launch_bounds__(256) void csr_scan_top(
    const int* __restrict__ btot, int* __restrict__ bbase)
{
    __shared__ int s[NBUK];
    const int t = threadIdx.x;
    const int v = btot[t];
    s[t] = v; __syncthreads();
    for (int st = 1; st < 256; st <<= 1) {
        const int u = (t >= st) ? s[t - st] : 0;
        __syncthreads();
        s[t] += u;
        __syncthreads();
    }
    bbase[t] = s[t] - v;
}

__global__ __launch_bounds__(256) void csr_scatter(
    const int* __restrict__ src, const int* __restrict__ dst,
    const int* __restrict__ basMat, const int* __restrict__ bbase,
    int2* __restrict__ binned)
{
    __shared__ int cur[NBUK];
    cur[threadIdx.x] = bbase[threadIdx.x] + basMat[threadIdx.x * NBLK + blockIdx.x];
    __syncthreads();
    const int e0 = blockIdx.x * EPB;
    const int e1 = min(e0 + EPB, N_EDGES);
    for (int e = e0 + threadIdx.x; e < e1; e += 256) {
        const int d = dst[e];
        const int pos = atomicAdd(&cur[d >> 9], 1);
        binned[pos] = make_int2(src[e], d);
    }
}

__global__ __launch_bounds__(256) void csr_build(
    const int2* __restrict__ binned, const int* __restrict__ bbase,
    const int* __restrict__ btot, int* __restrict__ rp, int* __restrict__ deg,
    float* __restrict__ inv, int* __restrict__ csr)
{
    __shared__ int hist[512];
    __shared__ int psc[256];
    __shared__ int cur[512];
    const int b = blockIdx.x, t = threadIdx.x;
    const int base = bbase[b];
    const int cntE = btot[b];
    const int n0 = b << 9;

    hist[t] = 0; hist[t + 256] = 0;
    __syncthreads();
    for (int i = t; i < cntE; i += 256)
        atomicAdd(&hist[binned[base + i].y - n0], 1);
    __syncthreads();

    const int h0 = hist[2 * t], h1 = hist[2 * t + 1];
    const int own = h0 + h1;
    psc[t] = own; __syncthreads();
    for (int st = 1; st < 256; st <<= 1) {
        const int u = (t >= st) ? psc[t - st] : 0;
        __syncthreads();
        psc[t] += u;
        __syncthreads();
    }
    const int pairExcl = psc[t] - own;
    cur[2 * t]     = pairExcl;
    cur[2 * t + 1] = pairExcl + h0;
    const int node0 = n0 + 2 * t, node1 = n0 + 2 * t + 1;
    if (node0 < N_NODES) {
        rp[node0] = base + pairExcl; deg[node0] = h0;
        inv[node0] = 1.f / fmaxf((float)h0, 1.f);
    }
    if (node1 < N_NODES) {
        rp[node1] = base + pairExcl + h0; deg[node1] = h1;
        inv[node1] = 1.f / fmaxf((float)h1, 1.f);
    }
    __syncthreads();
    for (int i = t; i < cntE; i += 256) {
        const int2 r = binned[base + i];
        const int pos = atomicAdd(&cur[r.y - n0], 1);
        csr[base + pos] = r.x;
    }
}

// ---------------------------------------------------------------------------
// Gather-mean: wave per node, 4x16-lane groups, uint4 per lane
// ---------------------------------------------------------------------------
__global__ __launch_bounds__(256) void gather_mean(
    const unsigned short* __restrict__ h, const int* __restrict__ csr,
    const int* __restrict__ rp, const int* __restrict__ deg,
    const float* __restrict__ inv, unsigned short* __restrict__ agg)
{
    const int wave   = (blockIdx.x * blockDim.x + threadIdx.x) >> 6;
    const int lane   = threadIdx.x & 63;
    const int grp    = lane >> 4;            // 0..3
    const int fl     = (lane & 15) * 8;      // feature base (8 bf16 = 16B)
    const int nwaves = (gridDim.x * blockDim.x) >> 6;

    for (int n = wave; n < N_NODES; n += nwaves) {
        const int s0 = rp[n];
        const int s1 = s0 + deg[n];
        float a[8];
#pragma unroll
        for (int k = 0; k < 8; k++) a[k] = 0.f;

        for (int j = s0 + grp; j < s1; j += 4) {
            const int s = csr[j];
            const uint4 v = *(const uint4*)&h[(size_t)s * D_H + fl];
            a[0] += bflo(v.x); a[1] += bfhi(v.x);
            a[2] += bflo(v.y); a[3] += bfhi(v.y);
            a[4] += bflo(v.z); a[5] += bfhi(v.z);
            a[6] += bflo(v.w); a[7] += bfhi(v.w);
        }
#pragma unroll
        for (int k = 0; k < 8; k++) a[k] += __shfl_xor(a[k], 16, 64);
#pragma unroll
        for (int k = 0; k < 8; k++) a[k] += __shfl_xor(a[k], 32, 64);

        if (grp == 0) {
            const float sc = inv[n];
            uint4 o;
            o.x = (unsigned)f2bf(a[0] * sc) | ((unsigned)f2bf(a[1] * sc) << 16);
            o.y = (unsigned)f2bf(a[2] * sc) | ((unsigned)f2bf(a[3] * sc) << 16);
            o.z = (unsigned)f2bf(a[4] * sc) | ((unsigned)f2bf(a[5] * sc) << 16);
            o.w = (unsigned)f2bf(a[6] * sc) | ((unsigned)f2bf(a[7] * sc) << 16);
            *(uint4*)&agg[(size_t)n * D_H + fl] = o;
        }
    }
}

// ---------------------------------------------------------------------------
// Pooling: one block per graph (batch sorted), direct mean+max
// ---------------------------------------------------------------------------
__global__ __launch_bounds__(256) void pool_graph(
    const unsigned short* __restrict__ h, const int* __restrict__ batch,
    float* __restrict__ meanb, float* __restrict__ maxb)
{
    __shared__ int bounds[2];
    __shared__ float2 ssum[256];
    __shared__ float2 smax[256];
    const int g = blockIdx.x, t = threadIdx.x;
    if (t < 2) {
        const int v = g + t;
        int lo = 0, hi = N_NODES;
        while (lo < hi) { const int m = (lo + hi) >> 1; if (batch[m] < v) lo = m + 1; else hi = m; }
        bounds[t] = lo;
    }
    __syncthreads();
    const int n0 = bounds[0], n1 = bounds[1];
    const int f2 = t & 63;
    const int sub = t >> 6;

    float sx = 0.f, sy = 0.f, mx = 0.f, my = 0.f;   // h >= 0 post-relu
    for (int n = n0 + sub; n < n1; n += 4) {
        const unsigned v = *(const unsigned*)&h[(size_t)n * D_H + f2 * 2];
        const float x = bflo(v), y = bfhi(v);
        sx += x; sy += y;
        mx = fmaxf(mx, x); my = fmaxf(my, y);
    }
    ssum[t] = make_float2(sx, sy);
    smax[t] = make_float2(mx, my);
    __syncthreads();
    if (sub == 0) {
        const float2 s0 = ssum[t], s1 = ssum[t + 64], s2 = ssum[t + 128], s3 = ssum[t + 192];
        const float2 m0 = smax[t], m1 = smax[t + 64], m2 = smax[t + 128], m3 = smax[t + 192];
        const float ic = 1.f / fmaxf((float)(n1 - n0), 1.f);
        meanb[g * D_H + f2 * 2]     = (s0.x + s1.x + s2.x + s3.x) * ic;
        meanb[g * D_H + f2 * 2 + 1] = (s0.y + s1.y + s2.y + s3.y) * ic;
        maxb[g * D_H + f2 * 2]      = fmaxf(fmaxf(m0.x, m1.x), fmaxf(m2.x, m3.x));
        maxb[g * D_H + f2 * 2 + 1]  = fmaxf(fmaxf(m0.y, m1.y), fmaxf(m2.y, m3.y));
    }
}

// ---------------------------------------------------------------------------
// Head MLP (fp32): z = [mean, max, gf]
// ---------------------------------------------------------------------------
__global__ __launch_bounds__(128) void mlp_kernel(
    const float* __restrict__ meanb, const float* __restrict__ maxb,
    const float* __restrict__ gf,
    const float* __restrict__ W1, const float* __restrict__ b1,
    const float* __restrict__ W2, const float* __restrict__ b2,
    float* __restrict__ out)
{
    __shared__ float z[2 * D_H + 32];
    __shared__ float z1[D_H];
    const int g = blockIdx.x, t = threadIdx.x;
    z[t]       = meanb[g * D_H + t];
    z[D_H + t] = maxb[g * D_H + t];
    if (t < 32) z[2 * D_H + t] = gf[g * 32 + t];
    __syncthreads();
    float a = b1[t];
    for (int k = 0; k < 2 * D_H + 32; k++) a += z[k] * W1[k * D_H + t];
    a = fmaxf(a, 0.f);
    z1[t] = a;
    __syncthreads();
    float o = b2[t];
    for (int k = 0; k < D_H; k++) o += z1[k] * W2[k * D_H + t];
    out[g * D_H + t] = fmaxf(o, 0.f);
}

// ---------------------------------------------------------------------------
extern "C" void kernel_launch(void* const* d_in, const int* in_sizes, int n_in,
                              void* d_out, int out_size, void* d_ws, size_t ws_size,
                              hipStream_t stream)
{
    const float* x     = (const float*)d_in[0];
    const int*   ei    = (const int*)d_in[1];
    const int*   batch = (const int*)d_in[2];
    const float* gf    = (const float*)d_in[3];
    const float* W_in  = (const float*)d_in[4];
    const float* b_in  = (const float*)d_in[5];
    const float* Wl    = (const float*)d_in[6];
    const float* bl    = (const float*)d_in[7];
    const float* Wr    = (const float*)d_in[8];
    const float* W1    = (const float*)d_in[9];
    const float* b1    = (const float*)d_in[10];
    const float* W2    = (const float*)d_in[11];
    const float* b2    = (const float*)d_in[12];
    float* out = (float*)d_out;

    const int* srcI = ei;
    const int* dstI = ei + N_EDGES;

    char* ws = (char*)d_ws;
    size_t off = 0;
    auto alloc = [&](size_t bytes) {
        char* p = ws + off;
        off += (bytes + 511) / 512 * 512;
        return p;
    };
    const size_t hB16 = (size_t)N_NODES * D_H * sizeof(unsigned short);
    unsigned short* bufA = (unsigned short*)alloc(hB16);
    unsigned short* bufB = (unsigned short*)alloc(hB16);
    unsigned short* PBin = (unsigned short*)alloc(128 * 128 * sizeof(unsigned short));
    unsigned short* PBl  = (unsigned short*)alloc((size_t)N_LAYERS * 128 * 256 * sizeof(unsigned short));
    int*   degI   = (int*)alloc(N_NODES * sizeof(int));
    float* inv    = (float*)alloc(N_NODES * sizeof(float));
    int*   rp     = (int*)alloc(N_NODES * sizeof(int));
    int*   csr    = (int*)alloc((size_t)N_EDGES * sizeof(int));
    int2*  binned = (int2*)alloc((size_t)N_EDGES * sizeof(int2));
    int*   cntMat = (int*)alloc((size_t)NBUK * NBLK * sizeof(int));
    int*   basMat = (int*)alloc((size_t)NBUK * NBLK * sizeof(int));
    int*   btot   = (int*)alloc(NBUK * sizeof(int));
    int*   bbase  = (int*)alloc(NBUK * sizeof(int));
    float* meanb  = (float*)alloc(N_GRAPHS * D_H * sizeof(float));
    float* maxb   = (float*)alloc(N_GRAPHS * D_H * sizeof(float));

    // CSR build (atomic-free, binned)
    csr_count<<<NBLK, 256, 0, stream>>>(dstI, cntMat);
    csr_scan_bucket<<<NBUK, 256, 0, stream>>>(cntMat, basMat, btot);
    csr_scan_top<<<1, 256, 0, stream>>>(btot, bbase);
    csr_scatter<<<NBLK, 256, 0, stream>>>(srcI, dstI, basMat, bbase, binned);
    csr_build<<<NBUK, 256, 0, stream>>>(binned, bbase, btot, rp, degI, inv, csr);

    prep_bt<<<(16384 + N_LAYERS * 32768 + 255) / 256, 256, 0, stream>>>(
        W_in, Wl, Wr, PBin, PBl);

    const int gblocks = (N_NODES + BM - 1) / BM;
    // input projection (fp32 x converted in staging): -> bufA
    gemm_mfma<0><<<gblocks, 256, 0, stream>>>(x, nullptr, nullptr, PBin, b_in, bufA, N_NODES);

    unsigned short* h   = bufA;
    unsigned short* agg = bufB;
    for (int l = 0; l < N_LAYERS; l++) {
        gather_mean<<<2048, 256, 0, stream>>>(h, csr, rp, degI, inv, agg);
        // out aliases agg (A0): safe, block-local rows only
        gemm_mfma<1><<<gblocks, 256, 0, stream>>>(nullptr, agg, h, PBl + (size_t)l * 32768,
                                                  bl + (size_t)l * D_H, agg, N_NODES);
        unsigned short* tmp = h; h = agg; agg = tmp;
    }

    pool_graph<<<N_GRAPHS, 256, 0, stream>>>(h, batch, meanb, maxb);
    mlp_kernel<<<N_GRAPHS, 128, 0, stream>>>(meanb, maxb, gf, W1, b1, W2, b2, out);
}

// Round 10
// 393.926 us; speedup vs baseline: 2.2010x; 1.0039x over previous
//
#include <hip/hip_runtime.h>

#define N_NODES  100000
#define N_EDGES  1600000
#define N_GRAPHS 512
#define D_H      128
#define N_LAYERS 3

typedef __attribute__((ext_vector_type(8))) short bf16x8;
typedef __attribute__((ext_vector_type(4))) float f32x4;

__device__ __forceinline__ unsigned short f2bf(float f) {
    unsigned int u = __float_as_uint(f);
    u += 0x7fffu + ((u >> 16) & 1u);          // RNE
    return (unsigned short)(u >> 16);
}
__device__ __forceinline__ float bf2f(unsigned short h) {
    return __uint_as_float(((unsigned int)h) << 16);
}
__device__ __forceinline__ float bflo(unsigned v) { return __uint_as_float(v << 16); }
__device__ __forceinline__ float bfhi(unsigned v) { return __uint_as_float(v & 0xffff0000u); }

#define BM  256   // rows per block (8 waves x 64 rows? no: 4 row-slots x 64)
#define BKP 72    // 64 + 8 pad ushorts (144B stride -> 2-way max, free)

// ---------------------------------------------------------------------------
// bf16 MFMA GEMM, 256x128 tile, 512 threads = 8 waves (4 row-slots x 2 col).
// A: LDS-staged 256x64 per K-step (36.9KB total). B: pre-packed MFMA fragment
// order, direct global (L2-resident, lane-contiguous 1KB/wave-load).
// MODE 0: A = Af fp32 (Ktot=128), converted during staging.
// MODE 1: A = concat-K [A0 | A1] bf16 (Ktot=256). out may alias A0 (each
// block stages its own A0 rows, barrier-protected, before the epilogue).
// ---------------------------------------------------------------------------
template <int MODE>
__global__ __launch_bounds__(512) void gemm_mfma(
    const float* __restrict__ Af, const unsigned short* A0,
    const unsigned short* A1, const unsigned short* __restrict__ PB,
    const float* __restrict__ bias, unsigned short* out, int M)
{
    constexpr int Ktot = (MODE == 0) ? 128 : 256;
    __shared__ unsigned short As[BM][BKP];

    const int t    = threadIdx.x;
    const int wave = t >> 6, lane = t & 63;
    const int wr   = wave >> 1, wc = wave & 1;   // wr 0..3, wc 0..1
    const int l15  = lane & 15;
    const int row0 = blockIdx.x * BM;

    f32x4 acc[4][4];
#pragma unroll
    for (int m = 0; m < 4; m++)
#pragma unroll
        for (int n = 0; n < 4; n++) acc[m][n] = (f32x4)0.f;

    for (int s = 0; s < (Ktot >> 6); s++) {
        const int kb = s * 64;
        __syncthreads();
        if (MODE == 0) {
#pragma unroll
            for (int it = 0; it < 4; it++) {
                const int idx = t + it * 512;       // 2048 uint4 slots
                const int r = idx >> 3, c8 = (idx & 7) * 8;
                uint4 o = make_uint4(0, 0, 0, 0);
                if (row0 + r < M) {
                    const float* p = &Af[(size_t)(row0 + r) * D_H + kb + c8];
                    const float4 v0 = *(const float4*)p;
                    const float4 v1 = *(const float4*)(p + 4);
                    o.x = (unsigned)f2bf(v0.x) | ((unsigned)f2bf(v0.y) << 16);
                    o.y = (unsigned)f2bf(v0.z) | ((unsigned)f2bf(v0.w) << 16);
                    o.z = (unsigned)f2bf(v1.x) | ((unsigned)f2bf(v1.y) << 16);
                    o.w = (unsigned)f2bf(v1.z) | ((unsigned)f2bf(v1.w) << 16);
                }
                *(uint4*)&As[r][c8] = o;
            }
        } else {
            const unsigned short* Asrc = (kb < 128) ? A0 : A1;
            const int ka = kb & 127;
#pragma unroll
            for (int it = 0; it < 4; it++) {
                const int idx = t + it * 512;
                const int r = idx >> 3, c8 = (idx & 7) * 8;
                uint4 v = make_uint4(0, 0, 0, 0);
                if (row0 + r < M)
                    v = *(const uint4*)&Asrc[(size_t)(row0 + r) * D_H + ka + c8];
                *(uint4*)&As[r][c8] = v;
            }
        }
        __syncthreads();

#pragma unroll
        for (int kk = 0; kk < 64; kk += 32) {
            const int koff = kk + (lane >> 4) * 8;
            const int kblk = (kb + kk) >> 5;
            bf16x8 af[4], bfr[4];
#pragma unroll
            for (int m = 0; m < 4; m++)
                af[m] = *(const bf16x8*)&As[wr * 64 + m * 16 + l15][koff];
#pragma unroll
            for (int n = 0; n < 4; n++)
                bfr[n] = *(const bf16x8*)&PB[(size_t)(((kblk << 3) + (wc << 2) + n) << 9) + lane * 8];
#pragma unroll
            for (int m = 0; m < 4; m++)
#pragma unroll
                for (int n = 0; n < 4; n++)
                    acc[m][n] = __builtin_amdgcn_mfma_f32_16x16x32_bf16(
                        af[m], bfr[n], acc[m][n], 0, 0, 0);
        }
    }

    float bv[4];
#pragma unroll
    for (int n = 0; n < 4; n++) bv[n] = bias[wc * 64 + n * 16 + l15];

#pragma unroll
    for (int m = 0; m < 4; m++) {
#pragma unroll
        for (int j = 0; j < 4; j++) {
            const int row = row0 + wr * 64 + m * 16 + (lane >> 4) * 4 + j;
            if (row < M) {
#pragma unroll
                for (int n = 0; n < 4; n++) {
                    const int col = wc * 64 + n * 16 + l15;
                    out[(size_t)row * D_H + col] = f2bf(fmaxf(acc[m][n][j] + bv[n], 0.f));
                }
            }
        }
    }
}

// ---------------------------------------------------------------------------
// Weight prep: pack transposed bf16 weights in MFMA fragment order.
// PB[((kblk*8 + nb)*64 + lane)*8 + j]: n = nb*16+(lane&15), k = kblk*32+(lane>>4)*8+j
// ---------------------------------------------------------------------------
__global__ __launch_bounds__(256) void prep_bt(
    const float* __restrict__ W_in, const float* __restrict__ Wl,
    const float* __restrict__ Wr, unsigned short* __restrict__ PBin,
    unsigned short* __restrict__ PBl)
{
    const int i = blockIdx.x * blockDim.x + threadIdx.x;
    if (i < 16384) {
        const int j = i & 7, lane = (i >> 3) & 63, nb = (i >> 9) & 7, kblk = i >> 12;
        const int n = nb * 16 + (lane & 15);
        const int k = kblk * 32 + ((lane >> 4) << 3) + j;
        PBin[i] = f2bf(W_in[k * 128 + n]);
    } else if (i < 16384 + N_LAYERS * 32768) {
        const int i2 = i - 16384;
        const int l = i2 >> 15, r = i2 & 32767;
        const int j = r & 7, lane = (r >> 3) & 63, nb = (r >> 9) & 7, kblk = (r >> 12) & 7;
        const int n = nb * 16 + (lane & 15);
        const int k = kblk * 32 + ((lane >> 4) << 3) + j;
        const float v = (k < 128) ? Wl[(size_t)l * 16384 + k * 128 + n]
                                  : Wr[(size_t)l * 16384 + (k - 128) * 128 + n];
        PBl[(size_t)l * 32768 + r] = f2bf(v);
    }
}

// ---------------------------------------------------------------------------
// CSR build via 256-bucket binning (bucket = dst>>9, 512 nodes each).
// ---------------------------------------------------------------------------
#define NBUK 256
#define EPB  8192
#define NBLK ((N_EDGES + EPB - 1) / EPB)     // 196

__global__ __launch_bounds__(256) void csr_count(
    const int* __restrict__ dst, int* __restrict__ cntMat)
{
    __shared__ int cnt[NBUK];
    cnt[threadIdx.x] = 0;
    __syncthreads();
    const int e0 = blockIdx.x * EPB;
    const int e1 = min(e0 + EPB, N_EDGES);
    for (int e = e0 + threadIdx.x; e < e1; e += 256)
        atomicAdd(&cnt[dst[e] >> 9], 1);
    __syncthreads();
    cntMat[threadIdx.x * NBLK + blockIdx.x] = cnt[threadIdx.x];
}

__global__ __launch_bounds__(256) void csr_scan_bucket(
    const int* __restrict__ cntMat, int* __restrict__ basMat, int* __restrict__ btot)
{
    __shared__ int s[256];
    const int b = blockIdx.x, t = threadIdx.x;
    const int v = (t < NBLK) ? cntMat[b * NBLK + t] : 0;
    s[t] = v; __syncthreads();
    for (int st = 1; st < 256; st <<= 1) {
        const int u = (t >= st) ? s[t - st] : 0;
        __syncthreads();
        s[t] += u;
        __syncthreads();
    }
    if (t < NBLK) basMat[b * NBLK + t] = s[t] - v;
    if (t == 255) btot[b] = s[255];
}

__global__ __launch_bounds__(256) void csr_scan_top(
    const int* __restrict__ btot, int* __restrict__ bbase)
{
    __shared__ int s[NBUK];
    const int t = threadIdx.x;
    const int v = btot[t];
    s[t] = v; __syncthreads();
    for (int st = 1; st < 256; st <<= 1) {
        const int u = (t >= st) ? s[t - st] : 0;
        __syncthreads();
        s[t] += u;
        __syncthreads();
    }
    bbase[t] = s[t] - v;
}

__global__ __launch_bounds__(256) void csr_scatter(
    const int* __restrict__ src, const int* __restrict__ dst,
    const int* __restrict__ basMat, const int* __restrict__ bbase,
    int2* __restrict__ binned)
{
    __shared__ int cur[NBUK];
    cur[threadIdx.x] = bbase[threadIdx.x] + basMat[threadIdx.x * NBLK + blockIdx.x];
    __syncthreads();
    const int e0 = blockIdx.x * EPB;
    const int e1 = min(e0 + EPB, N_EDGES);
    for (int e = e0 + threadIdx.x; e < e1; e += 256) {
        const int d = dst[e];
        const int pos = atomicAdd(&cur[d >> 9], 1);
        binned[pos] = make_int2(src[e], d);
    }
}

__global__ __launch_bounds__(256) void csr_build(
    const int2* __restrict__ binned, const int* __restrict__ bbase,
    const int* __restrict__ btot, int* __restrict__ rp, int* __restrict__ deg,
    float* __restrict__ inv, int* __restrict__ csr)
{
    __shared__ int hist[512];
    __shared__ int psc[256];
    __shared__ int cur[512];
    const int b = blockIdx.x, t = threadIdx.x;
    const int base = bbase[b];
    const int cntE = btot[b];
    const int n0 = b << 9;

    hist[t] = 0; hist[t + 256] = 0;
    __syncthreads();
    for (int i = t; i < cntE; i += 256)
        atomicAdd(&hist[binned[base + i].y - n0], 1);
    __syncthreads();

    const int h0 = hist[2 * t], h1 = hist[2 * t + 1];
    const int own = h0 + h1;
    psc[t] = own; __syncthreads();
    for (int st = 1; st < 256; st <<= 1) {
        const int u = (t >= st) ? psc[t - st] : 0;
        __syncthreads();
        psc[t] += u;
        __syncthreads();
    }
    const int pairExcl = psc[t] - own;
    cur[2 * t]     = pairExcl;
    cur[2 * t + 1] = pairExcl + h0;
    const int node0 = n0 + 2 * t, node1 = n0 + 2 * t + 1;
    if (node0 < N_NODES) {
        rp[node0] = base + pairExcl; deg[node0] = h0;
        inv[node0] = 1.f / fmaxf((float)h0, 1.f);
    }
    if (node1 < N_NODES) {
        rp[node1] = base + pairExcl + h0; deg[node1] = h1;
        inv[node1] = 1.f / fmaxf((float)h1, 1.f);
    }
    __syncthreads();
    for (int i = t; i < cntE; i += 256) {
        const int2 r = binned[base + i];
        const int pos = atomicAdd(&cur[r.y - n0], 1);
        csr[base + pos] = r.x;
    }
}

// ---------------------------------------------------------------------------
// Gather-mean: wave per node, 4x16-lane groups, uint4 per lane
// (at the ~6 TB/s fabric delivery ceiling — do not touch)
// ---------------------------------------------------------------------------
__global__ __launch_bounds__(256) void gather_mean(
    const unsigned short* __restrict__ h, const int* __restrict__ csr,
    const int* __restrict__ rp, const int* __restrict__ deg,
    const float* __restrict__ inv, unsigned short* __restrict__ agg)
{
    const int wave   = (blockIdx.x * blockDim.x + threadIdx.x) >> 6;
    const int lane   = threadIdx.x & 63;
    const int grp    = lane >> 4;            // 0..3
    const int fl     = (lane & 15) * 8;      // feature base (8 bf16 = 16B)
    const int nwaves = (gridDim.x * blockDim.x) >> 6;

    for (int n = wave; n < N_NODES; n += nwaves) {
        const int s0 = rp[n];
        const int s1 = s0 + deg[n];
        float a[8];
#pragma unroll
        for (int k = 0; k < 8; k++) a[k] = 0.f;

        for (int j = s0 + grp; j < s1; j += 4) {
            const int s = csr[j];
            const uint4 v = *(const uint4*)&h[(size_t)s * D_H + fl];
            a[0] += bflo(v.x); a[1] += bfhi(v.x);
            a[2] += bflo(v.y); a[3] += bfhi(v.y);
            a[4] += bflo(v.z); a[5] += bfhi(v.z);
            a[6] += bflo(v.w); a[7] += bfhi(v.w);
        }
#pragma unroll
        for (int k = 0; k < 8; k++) a[k] += __shfl_xor(a[k], 16, 64);
#pragma unroll
        for (int k = 0; k < 8; k++) a[k] += __shfl_xor(a[k], 32, 64);

        if (grp == 0) {
            const float sc = inv[n];
            uint4 o;
            o.x = (unsigned)f2bf(a[0] * sc) | ((unsigned)f2bf(a[1] * sc) << 16);
            o.y = (unsigned)f2bf(a[2] * sc) | ((unsigned)f2bf(a[3] * sc) << 16);
            o.z = (unsigned)f2bf(a[4] * sc) | ((unsigned)f2bf(a[5] * sc) << 16);
            o.w = (unsigned)f2bf(a[6] * sc) | ((unsigned)f2bf(a[7] * sc) << 16);
            *(uint4*)&agg[(size_t)n * D_H + fl] = o;
        }
    }
}

// ---------------------------------------------------------------------------
// Pooling: one block per graph (batch sorted), direct mean+max
// ---------------------------------------------------------------------------
__global__ __launch_bounds__(256) void pool_graph(
    const unsigned short* __restrict__ h, const int* __restrict__ batch,
    float* __restrict__ meanb, float* __restrict__ maxb)
{
    __shared__ int bounds[2];
    __shared__ float2 ssum[256];
    __shared__ float2 smax[256];
    const int g = blockIdx.x, t = threadIdx.x;
    if (t < 2) {
        const int v = g + t;
        int lo = 0, hi = N_NODES;
        while (lo < hi) { const int m = (lo + hi) >> 1; if (batch[m] < v) lo = m + 1; else hi = m; }
        bounds[t] = lo;
    }
    __syncthreads();
    const int n0 = bounds[0], n1 = bounds[1];
    const int f2 = t & 63;
    const int sub = t >> 6;

    float sx = 0.f, sy = 0.f, mx = 0.f, my = 0.f;   // h >= 0 post-relu
    for (int n = n0 + sub; n < n1; n += 4) {
        const unsigned v = *(const unsigned*)&h[(size_t)n * D_H + f2 * 2];
        const float x = bflo(v), y = bfhi(v);
        sx += x; sy += y;
        mx = fmaxf(mx, x); my = fmaxf(my, y);
    }
    ssum[t] = make_float2(sx, sy);
    smax[t] = make_float2(mx, my);
    __syncthreads();
    if (sub == 0) {
        const float2 s0 = ssum[t], s1 = ssum[t + 64], s2 = ssum[t + 128], s3 = ssum[t + 192];
        const float2 m0 = smax[t], m1 = smax[t + 64], m2 = smax[t + 128], m3 = smax[t + 192];
        const float ic = 1.f / fmaxf((float)(n1 - n0), 1.f);
        meanb[g * D_H + f2 * 2]     = (s0.x + s1.x + s2.x + s3.x) * ic;
        meanb[g * D_H + f2 * 2 + 1] = (s0.y + s1.y + s2.y + s3.y) * ic;
        maxb[g * D_H + f2 * 2]      = fmaxf(fmaxf(m0.x, m1.x), fmaxf(m2.x, m3.x));
        maxb[g * D_H + f2 * 2 + 1]  = fmaxf(fmaxf(m0.y, m1.y), fmaxf(m2.y, m3.y));
    }
}

// ---------------------------------------------------------------------------
// Head MLP (fp32): z = [mean, max, gf]
// ---------------------------------------------------------------------------
__global__ __launch_bounds__(128) void mlp_kernel(
    const float* __restrict__ meanb, const float* __restrict__ maxb,
    const float* __restrict__ gf,
    const float* __restrict__ W1, const float* __restrict__ b1,
    const float* __restrict__ W2, const float* __restrict__ b2,
    float* __restrict__ out)
{
    __shared__ float z[2 * D_H + 32];
    __shared__ float z1[D_H];
    const int g = blockIdx.x, t = threadIdx.x;
    z[t]       = meanb[g * D_H + t];
    z[D_H + t] = maxb[g * D_H + t];
    if (t < 32) z[2 * D_H + t] = gf[g * 32 + t];
    __syncthreads();
    float a = b1[t];
    for (int k = 0; k < 2 * D_H + 32; k++) a += z[k] * W1[k * D_H + t];
    a = fmaxf(a, 0.f);
    z1[t] = a;
    __syncthreads();
    float o = b2[t];
    for (int k = 0; k < D_H; k++) o += z1[k] * W2[k * D_H + t];
    out[g * D_H + t] = fmaxf(o, 0.f);
}

// ---------------------------------------------------------------------------
extern "C" void kernel_launch(void* const* d_in, const int* in_sizes, int n_in,
                              void* d_out, int out_size, void* d_ws, size_t ws_size,
                              hipStream_t stream)
{
    const float* x     = (const float*)d_in[0];
    const int*   ei    = (const int*)d_in[1];
    const int*   batch = (const int*)d_in[2];
    const float* gf    = (const float*)d_in[3];
    const float* W_in  = (const float*)d_in[4];
    const float* b_in  = (const float*)d_in[5];
    const float* Wl    = (const float*)d_in[6];
    const float* bl    = (const float*)d_in[7];
    const float* Wr    = (const float*)d_in[8];
    const float* W1    = (const float*)d_in[9];
    const float* b1    = (const float*)d_in[10];
    const float* W2    = (const float*)d_in[11];
    const float* b2    = (const float*)d_in[12];
    float* out = (float*)d_out;

    const int* srcI = ei;
    const int* dstI = ei + N_EDGES;

    char* ws = (char*)d_ws;
    size_t off = 0;
    auto alloc = [&](size_t bytes) {
        char* p = ws + off;
        off += (bytes + 511) / 512 * 512;
        return p;
    };
    const size_t hB16 = (size_t)N_NODES * D_H * sizeof(unsigned short);
    unsigned short* bufA = (unsigned short*)alloc(hB16);
    unsigned short* bufB = (unsigned short*)alloc(hB16);
    unsigned short* PBin = (unsigned short*)alloc(128 * 128 * sizeof(unsigned short));
    unsigned short* PBl  = (unsigned short*)alloc((size_t)N_LAYERS * 128 * 256 * sizeof(unsigned short));
    int*   degI   = (int*)alloc(N_NODES * sizeof(int));
    float* inv    = (float*)alloc(N_NODES * sizeof(float));
    int*   rp     = (int*)alloc(N_NODES * sizeof(int));
    int*   csr    = (int*)alloc((size_t)N_EDGES * sizeof(int));
    int2*  binned = (int2*)alloc((size_t)N_EDGES * sizeof(int2));
    int*   cntMat = (int*)alloc((size_t)NBUK * NBLK * sizeof(int));
    int*   basMat = (int*)alloc((size_t)NBUK * NBLK * sizeof(int));
    int*   btot   = (int*)alloc(NBUK * sizeof(int));
    int*   bbase  = (int*)alloc(NBUK * sizeof(int));
    float* meanb  = (float*)alloc(N_GRAPHS * D_H * sizeof(float));
    float* maxb   = (float*)alloc(N_GRAPHS * D_H * sizeof(float));

    // CSR build (atomic-free, binned)
    csr_count<<<NBLK, 256, 0, stream>>>(dstI, cntMat);
    csr_scan_bucket<<<NBUK, 256, 0, stream>>>(cntMat, basMat, btot);
    csr_scan_top<<<1, 256, 0, stream>>>(btot, bbase);
    csr_scatter<<<NBLK, 256, 0, stream>>>(srcI, dstI, basMat, bbase, binned);
    csr_build<<<NBUK, 256, 0, stream>>>(binned, bbase, btot, rp, degI, inv, csr);

    prep_bt<<<(16384 + N_LAYERS * 32768 + 255) / 256, 256, 0, stream>>>(
        W_in, Wl, Wr, PBin, PBl);

    const int gblocks = (N_NODES + BM - 1) / BM;
    // input projection (fp32 x converted in staging): -> bufA
    gemm_mfma<0><<<gblocks, 512, 0, stream>>>(x, nullptr, nullptr, PBin, b_in, bufA, N_NODES);

    unsigned short* h   = bufA;
    unsigned short* agg = bufB;
    for (int l = 0; l < N_LAYERS; l++) {
        gather_mean<<<2048, 256, 0, stream>>>(h, csr, rp, degI, inv, agg);
        // out aliases agg (A0): safe, block-local rows only
        gemm_mfma<1><<<gblocks, 512, 0, stream>>>(nullptr, agg, h, PBl + (size_t)l * 32768,
                                                  bl + (size_t)l * D_H, agg, N_NODES);
        unsigned short* tmp = h; h = agg; agg = tmp;
    }

    pool_graph<<<N_GRAPHS, 256, 0, stream>>>(h, batch, meanb, maxb);
    mlp_kernel<<<N_GRAPHS, 128, 0, stream>>>(meanb, maxb, gf, W1, b1, W2, b2, out);
}